// Round 13
// baseline (136.437 us; speedup 1.0000x reference)
//
#include <hip/hip_runtime.h>
#include <math.h>

// MelGaussianFilteredMSE:
//   diff = 10^(mo/10) - 10^(tg/10)            (B=32, F=1025, T=2000, fp32)
//   out  = mean( (M @ diff along F)^2 )       M is BANDED: half-width <= 10
//
// R12: requested-byte reduction. Best structures all serve requested bytes
// at ~5.3 TB/s composite (HBM+L3); duration == requested/5.3. So cut the
// halo: NOUT 106->205 (NCHUNK=5, 5*205=1025 exact) -> halo ratio
// 1.189->1.098, requested 660->576 MB. Keep grid balanced at 5 blocks/CU by
// halving the block: NT=128, CT=256 (float2/thread, same as R8's geometry
// per-thread). PF=7 ring (neutral in R11, protects in-flight at 10 waves/CU).
// s_load coeffs from pre-packed band (zero-coeff edge trick), as R8.

#define B_N 32
#define F_N 1025
#define T_N 2000

#define NOUT   205   // output rows per f-chunk; 5*205 = 1025 exactly
#define ROWS   225   // NOUT + 20 halo = 10*21 + 15 (partial last macro)
#define NCHUNK 5
#define NT     128   // threads per block (2 waves)
#define CT     256   // t-columns per block (128 threads * 2)
#define PF     7     // ring depth; 21 % 7 == 0 -> static slots
#define CBS    24    // band row stride in floats (96 B, float4-aligned)
#define BANDROWS (NCHUNK * NOUT)     // 1025 rows

#define K_E 0.33219280948873623f     // log2(10)/10 : 10^(x/10) = 2^(x*K_E)

__global__ void build_band(const float* __restrict__ M, float* __restrict__ band) {
    const int idx = blockIdx.x * 256 + threadIdx.x;
    if (idx >= BANDROWS * CBS) return;
    const int f = idx / CBS;
    const int j = idx - f * CBS;
    const int k = f - 10 + j;
    float v = 0.f;
    if (j < 21 && f < F_N && k >= 0 && k < F_N) v = M[(size_t)f * F_N + k];
    band[idx] = v;
}

__global__ __launch_bounds__(NT, 4)
void mel_mse_stream(const float* __restrict__ mo_g, const float* __restrict__ tg_g,
                    const float* __restrict__ band, float* __restrict__ partials) {
    __shared__ float red[NT];

    const int tid = threadIdx.x;
    const int t0  = blockIdx.x * CT;
    const int f0  = blockIdx.y * NOUT;   // uniform
    const int b   = blockIdx.z;          // uniform
    const int t   = t0 + tid * 2;
    const bool colv = (t + 1 < T_N);     // T_N even: pair fully valid or not
    const int  tc   = colv ? t : 0;
    const int  base = f0 - 10;

    const size_t colbase = ((size_t)b * F_N) * (size_t)T_N + tc;

    float2 w[21];                        // diff window (static-indexed)
    float2 ra[PF], rc[PF];               // raw prefetch rings (14 loads in flight)
    float  acc = 0.f;

    // issue stream row n into ring slot s; row math is scalar/uniform
    auto ISSUE = [&](int n, int s) {
        int g = base + n;
        g = g < 0 ? 0 : (g > F_N - 1 ? F_N - 1 : g);   // OOB -> coeff is 0
        const size_t off = colbase + (size_t)g * T_N;
        ra[s] = *reinterpret_cast<const float2*>(mo_g + off);
        rc[s] = *reinterpret_cast<const float2*>(tg_g + off);
    };
    auto CONS = [&](int s, int ws) {
        const float2 a = ra[s], c = rc[s];
        w[ws].x = exp2f(a.x * K_E) - exp2f(c.x * K_E);
        w[ws].y = exp2f(a.y * K_E) - exp2f(c.y * K_E);
    };
    // emit global output row frow; s0 = window slot of tap 0 (compile-time).
    // Coeff address is uniform -> s_load into SGPRs; FMA reads s-operand.
    auto OUT = [&](int frow, int s0) {
        const float4* c4 = reinterpret_cast<const float4*>(band + (size_t)frow * CBS);
        float cf[24];
#pragma unroll
        for (int q = 0; q < 6; ++q)
            *reinterpret_cast<float4*>(&cf[4 * q]) = c4[q];
        float2 o = make_float2(0.f, 0.f);
#pragma unroll
        for (int j = 0; j < 21; ++j) {
            const float2 wv = w[(s0 + j) % 21];
            o.x = fmaf(cf[j], wv.x, o.x);
            o.y = fmaf(cf[j], wv.y, o.y);
        }
        acc = fmaf(o.x, o.x, fmaf(o.y, o.y, acc));
    };

    // ---- prologue: rows 0..6 in flight ----
#pragma unroll
    for (int i = 0; i < PF; ++i) ISSUE(i, i);

    // ---- macro 0 (rows 0..20): fill window; first output at i==20 ----
#pragma unroll
    for (int i = 0; i < 21; ++i) {
        CONS(i % PF, i);
        ISSUE(i + PF, i % PF);                    // rows 7..27
        if (i == 20) OUT(f0, 0);
    }
    // ---- macros 1..9 (rows 21..209): one output per row ----
    for (int m = 1; m < 10; ++m) {
        const int nb = m * 21;                    // nb % 21 == 0 -> slot = i % PF
#pragma unroll
        for (int i = 0; i < 21; ++i) {
            CONS(i % PF, i);
            ISSUE(nb + i + PF, i % PF);           // rows nb+7 .. nb+27
            OUT(f0 + nb + i - 20, (i + 1) % 21);  // static slot base
        }
    }
    // ---- partial macro (rows 210..224): 15 rows, outputs 190..204 ----
    // 210 % 21 == 0 and 210 % 7 == 0 -> same static slot formulas.
#pragma unroll
    for (int i = 0; i < 15; ++i) {
        CONS(i % PF, i);
        if (210 + i + PF <= ROWS - 1)             // compile-time: issue rows 217..224
            ISSUE(210 + i + PF, i % PF);
        OUT(f0 + 210 + i - 20, (i + 1) % 21);
    }

    // ---- block reduction ----
    red[tid] = colv ? acc : 0.f;
    __syncthreads();
    for (int s = NT / 2; s > 0; s >>= 1) {
        if (tid < s) red[tid] += red[tid + s];
        __syncthreads();
    }
    if (tid == 0) {
        const int bid = blockIdx.x + gridDim.x * (blockIdx.y + gridDim.y * blockIdx.z);
        partials[bid] = red[0];
    }
}

__global__ void mel_mse_reduce(const float* __restrict__ partials, int n,
                               float* __restrict__ out) {
    __shared__ double red[256];
    double s = 0.0;
    for (int i = threadIdx.x; i < n; i += 256) s += (double)partials[i];
    red[threadIdx.x] = s;
    __syncthreads();
    for (int st = 128; st > 0; st >>= 1) {
        if (threadIdx.x < st) red[threadIdx.x] += red[threadIdx.x + st];
        __syncthreads();
    }
    if (threadIdx.x == 0)
        out[0] = (float)(red[0] / (double)((long long)B_N * F_N * T_N));
}

extern "C" void kernel_launch(void* const* d_in, const int* in_sizes, int n_in,
                              void* d_out, int out_size, void* d_ws, size_t ws_size,
                              hipStream_t stream) {
    const float* mo = (const float*)d_in[0];   // model_output (32,1025,2000) fp32
    const float* tg = (const float*)d_in[1];   // target       (32,1025,2000) fp32
    const float* M  = (const float*)d_in[2];   // transform_matrix (1025,1025) fp32
    float* out      = (float*)d_out;

    float* band     = (float*)d_ws;                      // 1025*24*4 = 98400 B
    float* partials = (float*)((char*)d_ws + 98432);     // 1280*4    =  5120 B

    build_band<<<(BANDROWS * CBS + 255) / 256, 256, 0, stream>>>(M, band);

    dim3 grid((T_N + CT - 1) / CT,             // 8 t-tiles
              NCHUNK,                          // 5 f-chunks
              B_N);                            // 32 batches -> 1280 blocks = 5/CU
    const int nparts = grid.x * grid.y * grid.z;

    mel_mse_stream<<<grid, NT, 0, stream>>>(mo, tg, band, partials);
    mel_mse_reduce<<<1, 256, 0, stream>>>(partials, nparts, out);
}

// Round 14
// 133.589 us; speedup vs baseline: 1.0213x; 1.0213x over previous
//
#include <hip/hip_runtime.h>
#include <math.h>

// MelGaussianFilteredMSE:
//   diff = 10^(mo/10) - 10^(tg/10)            (B=32, F=1025, T=2000, fp32)
//   out  = mean( (M @ diff along F)^2 )       M is BANDED: half-width <= 10
//
// R13 = R8 skeleton (CT=512 float2, NT=256, lb(256,4), PF=3 ring, s_load
// coeffs, zero-coeff edge handling) with ONE conceptual delta: raise
// resident waves/CU ~17 -> ~26 at (nearly) unchanged requested bytes.
//   NOUT 106 -> 85, NCHUNK 10 -> 13  => grid 1664 blocks = 6.5/CU
//   (VGPR=36 allows ~14 blocks/CU, so residency is grid-given, not capped).
//   Halo 105/85 = 1.235 vs 1.189 -> requested ~648 MB vs 660 (controlled).
// Cross-round evidence: composite service rate correlates with
// waves/CU x bytes/lane and R8 was grid-capped at 20 waves/CU.

#define B_N 32
#define F_N 1025
#define T_N 2000

#define NOUT   85    // output rows per f-chunk; streamed rows = 105 = 5*21
#define NCHUNK 13    // 13*85 = 1105 >= 1025
#define NT     256   // threads per block
#define CT     512   // t-columns per block (256 threads * 2)
#define PF     3     // ring depth; 21 % 3 == 0 -> static slots
#define CBS    24    // band row stride in floats (96 B, float4-aligned)
#define BANDROWS (NCHUNK * NOUT)     // 1105 rows; rows >= 1025 all-zero

#define K_E 0.33219280948873623f     // log2(10)/10 : 10^(x/10) = 2^(x*K_E)

__global__ void build_band(const float* __restrict__ M, float* __restrict__ band) {
    const int idx = blockIdx.x * 256 + threadIdx.x;
    if (idx >= BANDROWS * CBS) return;
    const int f = idx / CBS;
    const int j = idx - f * CBS;
    const int k = f - 10 + j;
    float v = 0.f;
    if (j < 21 && f < F_N && k >= 0 && k < F_N) v = M[(size_t)f * F_N + k];
    band[idx] = v;
}

__global__ __launch_bounds__(NT, 4)
void mel_mse_stream(const float* __restrict__ mo_g, const float* __restrict__ tg_g,
                    const float* __restrict__ band, float* __restrict__ partials) {
    __shared__ float red[NT];

    const int tid = threadIdx.x;
    const int t0  = blockIdx.x * CT;
    const int f0  = blockIdx.y * NOUT;   // uniform
    const int b   = blockIdx.z;          // uniform
    const int t   = t0 + tid * 2;
    const bool colv = (t + 1 < T_N);     // T_N even: pair fully valid or not
    const int  tc   = colv ? t : 0;
    const int  base = f0 - 10;

    const size_t colbase = ((size_t)b * F_N) * (size_t)T_N + tc;

    float2 w[21];                        // diff window (static-indexed)
    float2 ra[PF], rc[PF];               // raw prefetch rings
    float  acc = 0.f;

    // issue stream row n into ring slot s; row math is scalar/uniform
    auto ISSUE = [&](int n, int s) {
        int g = base + n;
        g = g < 0 ? 0 : (g > F_N - 1 ? F_N - 1 : g);   // OOB -> coeff is 0
        const size_t off = colbase + (size_t)g * T_N;
        ra[s] = *reinterpret_cast<const float2*>(mo_g + off);
        rc[s] = *reinterpret_cast<const float2*>(tg_g + off);
    };
    auto CONS = [&](int s, int ws) {
        const float2 a = ra[s], c = rc[s];
        w[ws].x = exp2f(a.x * K_E) - exp2f(c.x * K_E);
        w[ws].y = exp2f(a.y * K_E) - exp2f(c.y * K_E);
    };
    // emit global output row frow; s0 = window slot of tap 0 (compile-time).
    // Coeff address is uniform -> s_load into SGPRs; FMA reads s-operand.
    auto OUT = [&](int frow, int s0) {
        const float4* c4 = reinterpret_cast<const float4*>(band + (size_t)frow * CBS);
        float cf[24];
#pragma unroll
        for (int q = 0; q < 6; ++q)
            *reinterpret_cast<float4*>(&cf[4 * q]) = c4[q];
        float2 o = make_float2(0.f, 0.f);
#pragma unroll
        for (int j = 0; j < 21; ++j) {
            const float2 wv = w[(s0 + j) % 21];
            o.x = fmaf(cf[j], wv.x, o.x);
            o.y = fmaf(cf[j], wv.y, o.y);
        }
        acc = fmaf(o.x, o.x, fmaf(o.y, o.y, acc));
    };

    // ---- prologue: rows 0..2 in flight ----
#pragma unroll
    for (int i = 0; i < PF; ++i) ISSUE(i, i);

    // ---- macro 0 (rows 0..20): fill window; first output at i==20 ----
#pragma unroll
    for (int i = 0; i < 21; ++i) {
        CONS(i % PF, i);
        ISSUE(i + PF, i % PF);                    // rows 3..23
        if (i == 20) OUT(f0, 0);
    }
    // ---- macros 1..4 (rows 21..104): one output per row ----
    // (trailing over-issues are clamped-address loads, values unused)
    for (int m = 1; m < 5; ++m) {
        const int nb = m * 21;                    // 21 % PF == 0 -> slot = i % PF
#pragma unroll
        for (int i = 0; i < 21; ++i) {
            CONS(i % PF, i);
            ISSUE(nb + i + PF, i % PF);
            OUT(f0 + nb + i - 20, (i + 1) % 21);  // static slot base
        }
    }

    // ---- block reduction ----
    red[tid] = colv ? acc : 0.f;
    __syncthreads();
    for (int s = NT / 2; s > 0; s >>= 1) {
        if (tid < s) red[tid] += red[tid + s];
        __syncthreads();
    }
    if (tid == 0) {
        const int bid = blockIdx.x + gridDim.x * (blockIdx.y + gridDim.y * blockIdx.z);
        partials[bid] = red[0];
    }
}

__global__ void mel_mse_reduce(const float* __restrict__ partials, int n,
                               float* __restrict__ out) {
    __shared__ double red[256];
    double s = 0.0;
    for (int i = threadIdx.x; i < n; i += 256) s += (double)partials[i];
    red[threadIdx.x] = s;
    __syncthreads();
    for (int st = 128; st > 0; st >>= 1) {
        if (threadIdx.x < st) red[threadIdx.x] += red[threadIdx.x + st];
        __syncthreads();
    }
    if (threadIdx.x == 0)
        out[0] = (float)(red[0] / (double)((long long)B_N * F_N * T_N));
}

extern "C" void kernel_launch(void* const* d_in, const int* in_sizes, int n_in,
                              void* d_out, int out_size, void* d_ws, size_t ws_size,
                              hipStream_t stream) {
    const float* mo = (const float*)d_in[0];   // model_output (32,1025,2000) fp32
    const float* tg = (const float*)d_in[1];   // target       (32,1025,2000) fp32
    const float* M  = (const float*)d_in[2];   // transform_matrix (1025,1025) fp32
    float* out      = (float*)d_out;

    float* band     = (float*)d_ws;                      // 1105*24*4 = 106080 B
    float* partials = (float*)((char*)d_ws + 106496);    // 1664*4    =   6656 B

    build_band<<<(BANDROWS * CBS + 255) / 256, 256, 0, stream>>>(M, band);

    dim3 grid((T_N + CT - 1) / CT,             // 4 t-tiles
              NCHUNK,                          // 13 f-chunks
              B_N);                            // 32 batches -> 1664 blocks = 6.5/CU
    const int nparts = grid.x * grid.y * grid.z;

    mel_mse_stream<<<grid, NT, 0, stream>>>(mo, tg, band, partials);
    mel_mse_reduce<<<1, 256, 0, stream>>>(partials, nparts, out);
}

// Round 15
// 114.901 us; speedup vs baseline: 1.1874x; 1.1626x over previous
//
#include <hip/hip_runtime.h>
#include <math.h>

// MelGaussianFilteredMSE:
//   diff = 10^(mo/10) - 10^(tg/10)            (B=32, F=1025, T=2000, fp32)
//   out  = mean( (M @ diff along F)^2 )       M is BANDED: half-width <= 10
//
// R14 = R8 skeleton (CT=512 float2, NT=256, lb(256,4), PF=3 ring, s_load
// coeffs, zero-coeff edges) with ONE delta: NCHUNK 10 -> 8 (NOUT=129).
// Model from R8/R12/R13: composite requested-byte service saturates at
// ~5.3 TB/s for >=~16 resident waves/CU; dur = requested/5.3 on that
// branch. NCHUNK=8 keeps the knee (grid 1024 = 4 blocks/CU balanced,
// 16 waves/CU) while cutting requested 660 -> 610 MB (halo 1.229->1.163).

#define B_N 32
#define F_N 1025
#define T_N 2000

#define NOUT   129   // output rows per f-chunk; 8*129 = 1032 >= 1025
#define ROWS   149   // NOUT + 20 halo = 7*21 + 2 (2-row static tail)
#define NCHUNK 8
#define NT     256   // threads per block
#define CT     512   // t-columns per block (256 threads * 2)
#define PF     3     // ring depth; 21 % 3 == 0 -> static slots
#define CBS    24    // band row stride in floats (96 B, float4-aligned)
#define BANDROWS (NCHUNK * NOUT)     // 1032 rows; rows >= 1025 all-zero

#define K_E 0.33219280948873623f     // log2(10)/10 : 10^(x/10) = 2^(x*K_E)

__global__ void build_band(const float* __restrict__ M, float* __restrict__ band) {
    const int idx = blockIdx.x * 256 + threadIdx.x;
    if (idx >= BANDROWS * CBS) return;
    const int f = idx / CBS;
    const int j = idx - f * CBS;
    const int k = f - 10 + j;
    float v = 0.f;
    if (j < 21 && f < F_N && k >= 0 && k < F_N) v = M[(size_t)f * F_N + k];
    band[idx] = v;
}

__global__ __launch_bounds__(NT, 4)
void mel_mse_stream(const float* __restrict__ mo_g, const float* __restrict__ tg_g,
                    const float* __restrict__ band, float* __restrict__ partials) {
    __shared__ float red[NT];

    const int tid = threadIdx.x;
    const int t0  = blockIdx.x * CT;
    const int f0  = blockIdx.y * NOUT;   // uniform
    const int b   = blockIdx.z;          // uniform
    const int t   = t0 + tid * 2;
    const bool colv = (t + 1 < T_N);     // T_N even: pair fully valid or not
    const int  tc   = colv ? t : 0;
    const int  base = f0 - 10;

    const size_t colbase = ((size_t)b * F_N) * (size_t)T_N + tc;

    float2 w[21];                        // diff window (static-indexed)
    float2 ra[PF], rc[PF];               // raw prefetch rings
    float  acc = 0.f;

    // issue stream row n into ring slot s; row math is scalar/uniform
    auto ISSUE = [&](int n, int s) {
        int g = base + n;
        g = g < 0 ? 0 : (g > F_N - 1 ? F_N - 1 : g);   // OOB -> coeff is 0
        const size_t off = colbase + (size_t)g * T_N;
        ra[s] = *reinterpret_cast<const float2*>(mo_g + off);
        rc[s] = *reinterpret_cast<const float2*>(tg_g + off);
    };
    auto CONS = [&](int s, int ws) {
        const float2 a = ra[s], c = rc[s];
        w[ws].x = exp2f(a.x * K_E) - exp2f(c.x * K_E);
        w[ws].y = exp2f(a.y * K_E) - exp2f(c.y * K_E);
    };
    // emit global output row frow; s0 = window slot of tap 0 (compile-time).
    // Coeff address is uniform -> s_load into SGPRs; FMA reads s-operand.
    auto OUT = [&](int frow, int s0) {
        const float4* c4 = reinterpret_cast<const float4*>(band + (size_t)frow * CBS);
        float cf[24];
#pragma unroll
        for (int q = 0; q < 6; ++q)
            *reinterpret_cast<float4*>(&cf[4 * q]) = c4[q];
        float2 o = make_float2(0.f, 0.f);
#pragma unroll
        for (int j = 0; j < 21; ++j) {
            const float2 wv = w[(s0 + j) % 21];
            o.x = fmaf(cf[j], wv.x, o.x);
            o.y = fmaf(cf[j], wv.y, o.y);
        }
        acc = fmaf(o.x, o.x, fmaf(o.y, o.y, acc));
    };

    // ---- prologue: rows 0..2 in flight ----
#pragma unroll
    for (int i = 0; i < PF; ++i) ISSUE(i, i);

    // ---- macro 0 (rows 0..20): fill window; first output at i==20 ----
#pragma unroll
    for (int i = 0; i < 21; ++i) {
        CONS(i % PF, i);
        ISSUE(i + PF, i % PF);                    // rows 3..23
        if (i == 20) OUT(f0, 0);
    }
    // ---- macros 1..6 (rows 21..146): one output per row ----
    // (trailing over-issues are clamped-address loads, values unused)
    for (int m = 1; m < 7; ++m) {
        const int nb = m * 21;                    // 21 % PF == 0 -> slot = i % PF
#pragma unroll
        for (int i = 0; i < 21; ++i) {
            CONS(i % PF, i);
            ISSUE(nb + i + PF, i % PF);
            OUT(f0 + nb + i - 20, (i + 1) % 21);  // static slot base
        }
    }
    // ---- tail (rows 147..148): 2 rows; 147 % 21 == 0 and 147 % 3 == 0,
    // so the same static slot formulas hold with i = 0,1 ----
#pragma unroll
    for (int i = 0; i < 2; ++i) {
        CONS(i % PF, i);
        OUT(f0 + 147 + i - 20, (i + 1) % 21);
    }

    // ---- block reduction ----
    red[tid] = colv ? acc : 0.f;
    __syncthreads();
    for (int s = NT / 2; s > 0; s >>= 1) {
        if (tid < s) red[tid] += red[tid + s];
        __syncthreads();
    }
    if (tid == 0) {
        const int bid = blockIdx.x + gridDim.x * (blockIdx.y + gridDim.y * blockIdx.z);
        partials[bid] = red[0];
    }
}

__global__ void mel_mse_reduce(const float* __restrict__ partials, int n,
                               float* __restrict__ out) {
    __shared__ double red[256];
    double s = 0.0;
    for (int i = threadIdx.x; i < n; i += 256) s += (double)partials[i];
    red[threadIdx.x] = s;
    __syncthreads();
    for (int st = 128; st > 0; st >>= 1) {
        if (threadIdx.x < st) red[threadIdx.x] += red[threadIdx.x + st];
        __syncthreads();
    }
    if (threadIdx.x == 0)
        out[0] = (float)(red[0] / (double)((long long)B_N * F_N * T_N));
}

extern "C" void kernel_launch(void* const* d_in, const int* in_sizes, int n_in,
                              void* d_out, int out_size, void* d_ws, size_t ws_size,
                              hipStream_t stream) {
    const float* mo = (const float*)d_in[0];   // model_output (32,1025,2000) fp32
    const float* tg = (const float*)d_in[1];   // target       (32,1025,2000) fp32
    const float* M  = (const float*)d_in[2];   // transform_matrix (1025,1025) fp32
    float* out      = (float*)d_out;

    float* band     = (float*)d_ws;                      // 1032*24*4 = 99072 B
    float* partials = (float*)((char*)d_ws + 99328);     // 1024*4    =  4096 B

    build_band<<<(BANDROWS * CBS + 255) / 256, 256, 0, stream>>>(M, band);

    dim3 grid((T_N + CT - 1) / CT,             // 4 t-tiles
              NCHUNK,                          // 8 f-chunks
              B_N);                            // 32 batches -> 1024 blocks = 4/CU
    const int nparts = grid.x * grid.y * grid.z;

    mel_mse_stream<<<grid, NT, 0, stream>>>(mo, tg, band, partials);
    mel_mse_reduce<<<1, 256, 0, stream>>>(partials, nparts, out);
}